// Round 2
// 432.444 us; speedup vs baseline: 1.4813x; 1.4813x over previous
//
#include <hip/hip_runtime.h>
#include <math.h>

#define N_   8
#define C_   64
#define H_   128
#define W_   128
#define HW_  (H_ * W_)
#define CHW_ (C_ * HW_)
#define K_   3
#define CI_TILE 8
#define CO_BLK  16              // co channels per block
#define N_CG    (C_ / CO_BLK)   // 4 co-groups
#define TILE 16
#define HALO (TILE + 2)          // 18
#define LDS_STRIDE (HALO + 1)    // 19, +1 pad to break bank conflicts
#define WSTRIDE (C_ * K_ * K_)   // 576 floats between consecutive co's
#define BN_EPS 1e-5
#define POW_EPS 1e-12f

// Kernel 1: y[n,co,h,w] = -sum_{ci,kh,kw} |x[n,ci,h+kh-1,w+kw-1] - W[co,ci,kh,kw]| + x[n,co,h,w]
// co is split across gridDim.z (16 co per block) so the grid is 2048 blocks
// (8 blocks/CU -> 32 waves/CU) instead of 512 (2 blocks/CU). Per-channel
// sum/sumsq for BN are fused into the epilogue (values already in registers).
__global__ __launch_bounds__(256, 8) void adder_kernel(
    const float* __restrict__ x, const float* __restrict__ weight,
    float* __restrict__ y, double* __restrict__ sums)
{
    __shared__ float sx[CI_TILE][HALO][LDS_STRIDE];   // ~10.9 KB
    __shared__ float red[CO_BLK][2][4];               // per-wave stat partials

    const int tx = threadIdx.x & 15;
    const int ty = threadIdx.x >> 4;
    const int tile_h = blockIdx.x >> 3;   // H_/TILE = 8 tiles
    const int tile_w = blockIdx.x & 7;    // W_/TILE = 8 tiles
    const int n   = blockIdx.y;
    const int co0 = blockIdx.z * CO_BLK;
    const int h0 = tile_h * TILE;
    const int w0 = tile_w * TILE;

    float acc[CO_BLK];
#pragma unroll
    for (int j = 0; j < CO_BLK; ++j) acc[j] = 0.f;

    const float* xn = x + n * CHW_;

    for (int cb = 0; cb < C_; cb += CI_TILE) {
        __syncthreads();  // protect previous chunk's reads before overwrite
        // Stage CI_TILE x 18 x 18 halo tile, zero-filled outside image.
        for (int idx = threadIdx.x; idx < CI_TILE * HALO * HALO; idx += 256) {
            int ci  = idx / (HALO * HALO);
            int rem = idx - ci * (HALO * HALO);
            int r   = rem / HALO;
            int cc  = rem - r * HALO;
            int gh  = h0 + r - 1;
            int gw  = w0 + cc - 1;
            float v = 0.f;
            if ((unsigned)gh < (unsigned)H_ && (unsigned)gw < (unsigned)W_)
                v = xn[(cb + ci) * HW_ + gh * W_ + gw];
            sx[ci][r][cc] = v;
        }
        __syncthreads();

#pragma unroll 1
        for (int ci = 0; ci < CI_TILE; ++ci) {
            float xv[9];
#pragma unroll
            for (int kh = 0; kh < 3; ++kh)
#pragma unroll
                for (int kw = 0; kw < 3; ++kw)
                    xv[kh * 3 + kw] = sx[ci][ty + kh][tx + kw];

            // Wave-uniform weight pointer -> scalar loads.
            const float* wp = weight + co0 * WSTRIDE + (cb + ci) * (K_ * K_);
#pragma unroll
            for (int j = 0; j < CO_BLK; ++j) {
                const float* wc = wp + j * WSTRIDE;
#pragma unroll
                for (int k = 0; k < 9; ++k)
                    acc[j] += fabsf(xv[k] - wc[k]);
            }
        }
    }

    // Epilogue: y = -acc + residual x; fused per-channel sum/sumsq for BN.
    const int pix = (h0 + ty) * W_ + (w0 + tx);
    float* yo = y + n * CHW_ + co0 * HW_ + pix;
    const float* xr = xn + co0 * HW_ + pix;
    const int lane = threadIdx.x & 63;
    const int wid  = threadIdx.x >> 6;

#pragma unroll
    for (int j = 0; j < CO_BLK; ++j) {
        float v = -acc[j] + xr[j * HW_];
        yo[j * HW_] = v;
        float s = v, ss = v * v;
#pragma unroll
        for (int off = 32; off > 0; off >>= 1) {
            s  += __shfl_down(s, off);
            ss += __shfl_down(ss, off);
        }
        if (lane == 0) { red[j][0][wid] = s; red[j][1][wid] = ss; }
    }
    __syncthreads();
    if (threadIdx.x < CO_BLK) {
        int j = threadIdx.x;
        float S  = red[j][0][0] + red[j][0][1] + red[j][0][2] + red[j][0][3];
        float SS = red[j][1][0] + red[j][1][1] + red[j][1][2] + red[j][1][3];
        atomicAdd(&sums[co0 + j], (double)S);
        atomicAdd(&sums[C_ + co0 + j], (double)SS);
    }
}

// Kernel 3: per-channel scale/shift from batch stats.
__global__ void finalize_kernel(const double* __restrict__ sums,
                                const float* __restrict__ gamma,
                                const float* __restrict__ beta,
                                float* __restrict__ sc)
{
    const int c = threadIdx.x;  // 64 threads
    const double cnt = (double)(N_ * HW_);
    double mean = sums[c] / cnt;
    double var  = sums[C_ + c] / cnt - mean * mean;
    float inv   = (float)(1.0 / sqrt(var + (double)BN_EPS));
    float scale = gamma[c] * inv;
    float shift = beta[c] - (float)mean * scale;
    sc[c]      = scale;
    sc[C_ + c] = shift;
}

// Kernel 4: in-place BN affine + power activation, float4 vectorized.
__global__ __launch_bounds__(256) void apply_kernel(
    float* __restrict__ y, const float* __restrict__ sc,
    const float* __restrict__ alpha_p)
{
    const int idx = blockIdx.x * 256 + threadIdx.x;   // float4 index
    const float alpha = alpha_p[0];
    const int e0 = idx * 4;
    const int c = (e0 / HW_) & (C_ - 1);   // HW_ divisible by 4: all 4 in same channel
    const float scale = sc[c];
    const float shift = sc[C_ + c];

    float4 v = reinterpret_cast<float4*>(y)[idx];
    float* pv = reinterpret_cast<float*>(&v);
#pragma unroll
    for (int i = 0; i < 4; ++i) {
        float t = pv[i] * scale + shift;
        float sgn = (t > 0.f) ? 1.f : ((t < 0.f) ? -1.f : 0.f);
        pv[i] = sgn * powf(fabsf(t) + POW_EPS, alpha);
    }
    reinterpret_cast<float4*>(y)[idx] = v;
}

extern "C" void kernel_launch(void* const* d_in, const int* in_sizes, int n_in,
                              void* d_out, int out_size, void* d_ws, size_t ws_size,
                              hipStream_t stream)
{
    const float* x      = (const float*)d_in[0];
    const float* weight = (const float*)d_in[1];
    const float* gamma  = (const float*)d_in[2];
    const float* beta   = (const float*)d_in[3];
    const float* alpha  = (const float*)d_in[4];
    float* out = (float*)d_out;

    double* sums = (double*)d_ws;                                // 128 doubles
    float*  sc   = (float*)((char*)d_ws + 128 * sizeof(double)); // 128 floats

    hipMemsetAsync(d_ws, 0, 128 * sizeof(double), stream);

    adder_kernel<<<dim3(64, N_, N_CG), 256, 0, stream>>>(x, weight, out, sums);
    finalize_kernel<<<1, C_, 0, stream>>>(sums, gamma, beta, sc);

    const int n4 = (N_ * CHW_) / 4;           // 2,097,152 float4s
    apply_kernel<<<n4 / 256, 256, 0, stream>>>(out, sc, alpha);
}